// Round 3
// baseline (144.327 us; speedup 1.0000x reference)
//
#include <hip/hip_runtime.h>
#include <hip/hip_bf16.h>
#include <cstddef>

// Shapes (fixed by the problem)
#define BB 8
#define TT 512
#define CC 512
#define NHH 8
#define HDD 64

typedef __attribute__((ext_vector_type(8))) short short8;
typedef __attribute__((ext_vector_type(4))) float f32x4;

__device__ __forceinline__ unsigned short f2bf(float f) {
    unsigned u = __float_as_uint(f);
    u += 0x7FFFu + ((u >> 16) & 1u);
    return (unsigned short)(u >> 16);
}
__device__ __forceinline__ float bf2f(unsigned short h) {
    return __uint_as_float(((unsigned)h) << 16);
}

// ---------------------------------------------------------------------------
// Kernel 0: fp32 -> bf16 convert, WEIGHTS + REL only (x is converted in-flight
// by qkvln_k's A-staging). [0,768) w_attn, [768,1024) w_proj, [1024,1280) rel.
// ---------------------------------------------------------------------------
__global__ __launch_bounds__(256) void cvt_w_k(
    const float* __restrict__ wa, const float* __restrict__ wp,
    const float* __restrict__ rel,
    unsigned short* __restrict__ Wqb, unsigned short* __restrict__ Wpb,
    unsigned short* __restrict__ Relb)
{
    const int bidx = blockIdx.x;
    const float* in;
    unsigned short* out;
    int base;
    if (bidx < 768)       { in = wa;  out = Wqb;  base = bidx; }
    else if (bidx < 1024) { in = wp;  out = Wpb;  base = bidx - 768; }
    else                  { in = rel; out = Relb; base = bidx - 1024; }
    const int i = base * 1024 + threadIdx.x * 4;
    const float4 v = *(const float4*)(in + i);
    unsigned short tmp[4] = {f2bf(v.x), f2bf(v.y), f2bf(v.z), f2bf(v.w)};
    *(uint2*)(out + i) = *(const uint2*)tmp;
}

// ---------------------------------------------------------------------------
// Kernel 1: fused QKV GEMM + LayerNorm(q,k) + head-major scatter + V transpose.
//   R9 structure: 64x512 tile per block (one stream), grid 192 = 3 streams x
//   64 slabs = 1 block/CU. B (w_attn bf16) loads global->reg double-buffered
//   (zero cross-wave reuse -> LDS staging was pure overhead). Only A (x, fp32,
//   converted in-flight) goes through LDS (8KB/step). Full-width rows let LN
//   fuse into the epilogue: kills ln_k, the qkbuf round trip, and cvt-of-x.
//   q-stream output pre-scaled by 0.125*log2(e) (scores -> log2 domain).
// ---------------------------------------------------------------------------
#define QSTAGE_A()                                                            \
    __syncthreads();                                                          \
    _Pragma("unroll")                                                         \
    for (int l = 0; l < 2; ++l) {                                             \
        unsigned short t8[8];                                                 \
        _Pragma("unroll")                                                     \
        for (int e = 0; e < 4; ++e) {                                         \
            t8[e] = f2bf(ap[l][0][e]);                                        \
            t8[4 + e] = f2bf(ap[l][1][e]);                                    \
        }                                                                     \
        *(short8*)&smem[dstA[l]] = *(const short8*)t8;                        \
    }                                                                         \
    __syncthreads();

#define QLOADA(koff)                                                          \
    _Pragma("unroll")                                                         \
    for (int l = 0; l < 2; ++l) {                                             \
        ap[l][0] = *(const f32x4*)(srcA[l] + (koff));                         \
        ap[l][1] = *(const f32x4*)(srcA[l] + (koff) + 4);                     \
    }

#define QLOADB(bN, koff)                                                      \
    _Pragma("unroll")                                                         \
    for (int kk = 0; kk < 2; ++kk)                                            \
        _Pragma("unroll")                                                     \
        for (int j = 0; j < 8; ++j)                                           \
            bN[kk * 8 + j] =                                                  \
                *(const short8*)(Bb + (size_t)j * 8192 + kk * 32 + (koff));

#define QCOMPUTE(bN)                                                          \
    _Pragma("unroll")                                                         \
    for (int kk = 0; kk < 2; ++kk) {                                          \
        short8 af[4];                                                         \
        _Pragma("unroll")                                                     \
        for (int i = 0; i < 4; ++i)                                           \
            af[i] = *(const short8*)&smem[((i << 1) | kk) * 512 + lane * 8];  \
        _Pragma("unroll")                                                     \
        for (int j = 0; j < 8; ++j)                                           \
            _Pragma("unroll")                                                 \
            for (int i = 0; i < 4; ++i)                                       \
                acc[i][j] = __builtin_amdgcn_mfma_f32_16x16x32_bf16(          \
                    af[i], bN[kk * 8 + j], acc[i][j], 0, 0, 0);               \
    }

__global__ __launch_bounds__(256, 1) void qkvln_k(
    const float* __restrict__ x, const unsigned short* __restrict__ Wqb,
    const float* __restrict__ b_attn,
    const float* __restrict__ qg, const float* __restrict__ qb,
    const float* __restrict__ kg, const float* __restrict__ kb,
    unsigned short* __restrict__ Qh, unsigned short* __restrict__ Kh,
    unsigned short* __restrict__ VT)
{
    // A-stage frag rows [0,8)*512 during k-loop; reused as v-transpose buffer
    // (pitch 68 u16) or LN partial-sums (float2[4][64]) in the epilogue.
    __shared__ __align__(16) unsigned short smem[512 * 68];

    const int tid = threadIdx.x;
    const int w = tid >> 6, lane = tid & 63;
    const int c = lane & 15, quad = lane >> 4;

    const int strm = blockIdx.x >> 6;     // 0=q 1=k 2=v
    const int slab = blockIdx.x & 63;
    const int row0 = slab * 64;
    const int bi = row0 >> 9, trow0 = row0 & 511;

    // A staging map: 2 chunks/thread, frag-row fr = m16*2+kk
    const float* srcA[2];
    int dstA[2];
#pragma unroll
    for (int l = 0; l < 2; ++l) {
        const int idx = l * 256 + tid;
        const int fr = idx >> 6, li = idx & 63;
        srcA[l] = x + (size_t)(row0 + (fr >> 1) * 16 + (li & 15)) * 512
                    + (fr & 1) * 32 + (li >> 4) * 8;
        dstA[l] = fr * 512 + li * 8;
    }
    const unsigned short* Bb =
        Wqb + (size_t)(strm * 512 + w * 128 + c) * 512 + quad * 8;

    f32x4 acc[4][8];
#pragma unroll
    for (int i = 0; i < 4; ++i)
#pragma unroll
        for (int j = 0; j < 8; ++j) acc[i][j] = (f32x4){0.f, 0.f, 0.f, 0.f};

    f32x4 ap[2][2];
    short8 b0[16], b1[16];
    QLOADA(0);
    QLOADB(b0, 0);

#pragma unroll
    for (int kp = 0; kp < 4; ++kp) {
        const int ka = kp * 128;
        QSTAGE_A();                               // stages A(ka)
        QLOADA(ka + 64);
        QLOADB(b1, ka + 64);
        QCOMPUTE(b0);
        QSTAGE_A();                               // stages A(ka+64)
        if (kp < 3) {
            QLOADA(ka + 128);
            QLOADB(b0, ka + 128);
        }
        QCOMPUTE(b1);
    }

    // ---- epilogue: bias add ----
    {
        const int gcb = strm * 512 + w * 128;
#pragma unroll
        for (int j = 0; j < 8; ++j) {
            const float bj = b_attn[gcb + j * 16 + c];
#pragma unroll
            for (int i = 0; i < 4; ++i)
#pragma unroll
                for (int r = 0; r < 4; ++r) acc[i][j][r] += bj;
        }
    }

    if (strm < 2) {
        // -------- LayerNorm over the full 512 cols of each of 64 rows -------
        float s1[4][4], s2[4][4];
#pragma unroll
        for (int i = 0; i < 4; ++i)
#pragma unroll
            for (int r = 0; r < 4; ++r) {
                float a1 = 0.f, a2 = 0.f;
#pragma unroll
                for (int j = 0; j < 8; ++j) {
                    const float v = acc[i][j][r];
                    a1 += v;
                    a2 += v * v;
                }
#pragma unroll
                for (int off = 1; off < 16; off <<= 1) {
                    a1 += __shfl_xor(a1, off);
                    a2 += __shfl_xor(a2, off);
                }
                s1[i][r] = a1;
                s2[i][r] = a2;
            }
        __syncthreads();          // all waves done reading A frags from smem
        if (c == 0) {
#pragma unroll
            for (int i = 0; i < 4; ++i)
#pragma unroll
                for (int r = 0; r < 4; ++r)
                    ((float2*)smem)[w * 64 + i * 16 + quad * 4 + r] =
                        make_float2(s1[i][r], s2[i][r]);
        }
        __syncthreads();
        float rsg[4][4], nmu[4][4];
#pragma unroll
        for (int i = 0; i < 4; ++i)
#pragma unroll
            for (int r = 0; r < 4; ++r) {
                float a1 = 0.f, a2 = 0.f;
#pragma unroll
                for (int ww = 0; ww < 4; ++ww) {
                    const float2 t =
                        ((const float2*)smem)[ww * 64 + i * 16 + quad * 4 + r];
                    a1 += t.x;
                    a2 += t.y;
                }
                const float mu = a1 * (1.f / 512.f);
                const float var = a2 * (1.f / 512.f) - mu * mu;
                const float rs = rsqrtf(var + 1e-5f);
                rsg[i][r] = rs;
                nmu[i][r] = -mu * rs;
            }
        // fold softmax scale * log2(e) into q gamma/beta (scores -> log2 dom)
        const float osc = (strm == 0) ? 0.1803368801f : 1.0f;
        const float* gam = (strm == 0) ? qg : kg;
        const float* bet = (strm == 0) ? qb : kb;
        float gv[8], bv[8];
#pragma unroll
        for (int j = 0; j < 8; ++j) {
            gv[j] = gam[w * 128 + j * 16 + c] * osc;
            bv[j] = bet[w * 128 + j * 16 + c] * osc;
        }
        unsigned short* op =
            ((strm == 0) ? Qh : Kh) + (size_t)bi * (NHH * TT * HDD);
#pragma unroll
        for (int j = 0; j < 8; ++j) {
            const int gc = w * 128 + j * 16 + c;
            unsigned short* opc =
                op + (size_t)(gc >> 6) * (TT * HDD) + (gc & 63);
#pragma unroll
            for (int i = 0; i < 4; ++i)
#pragma unroll
                for (int r = 0; r < 4; ++r) {
                    const int trow = trow0 + i * 16 + quad * 4 + r;
                    const float t = fmaf(acc[i][j][r], rsg[i][r], nmu[i][r]);
                    opc[(size_t)trow * HDD] = f2bf(fmaf(t, gv[j], bv[j]));
                }
        }
    } else {
        // -------- v: transpose 64x512 -> VT[b][h][d][t] via LDS -------------
        __syncthreads();          // all waves done reading A frags from smem
#pragma unroll
        for (int i = 0; i < 4; ++i)
#pragma unroll
            for (int j = 0; j < 8; ++j) {
                const int col = w * 128 + j * 16 + c;      // vd 0..511
                const int rowt = i * 16 + quad * 4;        // local t
                unsigned short t4[4];
#pragma unroll
                for (int r = 0; r < 4; ++r) t4[r] = f2bf(acc[i][j][r]);
                *(uint2*)&smem[col * 68 + rowt] = *(const uint2*)t4;
            }
        __syncthreads();
#pragma unroll
        for (int l = 0; l < 16; ++l) {
            const int idx = l * 256 + tid;                 // 4096 8-elem chunks
            const int col = idx >> 3, part = idx & 7;
            const uint2 lo = *(const uint2*)&smem[col * 68 + part * 8];
            const uint2 hi = *(const uint2*)&smem[col * 68 + part * 8 + 4];
            uint2 pair[2] = {lo, hi};
            *(short8*)(VT + ((size_t)(bi * NHH + (col >> 6)) * HDD + (col & 63)) * TT
                       + trow0 + part * 8) = *(const short8*)pair;
        }
    }
}

// ---------------------------------------------------------------------------
// Kernel 2: MFMA flash attention with relative-position bias (R8, unchanged).
// ---------------------------------------------------------------------------
#define RD_BODY(nr_)                                                            \
    {                                                                           \
        const short8 br0 = *(const short8*)&Rels[((nr_) * 2 + 0) * 512 + lane * 8]; \
        const short8 br1 = *(const short8*)&Rels[((nr_) * 2 + 1) * 512 + lane * 8]; \
        f32x4 a2 = (f32x4){0.f, 0.f, 0.f, 0.f};                                 \
        a2 = __builtin_amdgcn_mfma_f32_16x16x32_bf16(aq0, br0, a2, 0, 0, 0);    \
        a2 = __builtin_amdgcn_mfma_f32_16x16x32_bf16(aq1, br1, a2, 0, 0, 0);    \
        const int colw = (mbase + (nr_) * 16 + c) & 127;                        \
        _Pragma("unroll")                                                       \
        for (int r = 0; r < 4; ++r)                                             \
            RDs[w][(quad * 4 + r) * 132 + colw] = f2bf(a2[r]);                  \
    }

__global__ __launch_bounds__(256, 2) void attn_k(
    const unsigned short* __restrict__ Qh, const unsigned short* __restrict__ Kh,
    const unsigned short* __restrict__ VT, const unsigned short* __restrict__ Relb,
    unsigned short* __restrict__ Yb)
{
    __shared__ __align__(16) unsigned short Ks[8 * 512];
    __shared__ __align__(16) unsigned short Vs[8 * 512];
    __shared__ __align__(16) unsigned short Rels[16 * 512];
    __shared__ __align__(16) unsigned short Ps[4][16 * 72];
    __shared__ __align__(16) unsigned short RDs[4][16 * 132];

    const int tid = threadIdx.x;
    const int w = tid >> 6;
    const int lane = tid & 63;
    const int c = lane & 15;
    const int quad = lane >> 4;

    // pairing-robust balanced decode
    const int bid = blockIdx.x;
    const int bit0 = bid & 1, bit8 = (bid >> 8) & 1;
    const int s_ = bit0 ^ bit8;
    const int q0 = (bid >> 1) & 7;
    const int qt = s_ ? 7 - q0 : q0;
    const int h = (bid >> 4) & 7;
    const int b = ((bid >> 7) & 1) | (bit8 << 1) | (bit0 << 2);
    const int i0 = qt * 64;

    const unsigned short* Qbase = Qh + (size_t)(b * NHH + h) * TT * HDD;
    const unsigned short* Kbase = Kh + (size_t)(b * NHH + h) * TT * HDD;
    const unsigned short* Vbase = VT + (size_t)(b * NHH + h) * HDD * TT;
    const unsigned short* Rbase = Relb + h * HDD;

    // Q: direct global -> registers
    const unsigned short* qp = Qbase + (size_t)(i0 + w * 16 + c) * HDD + quad * 8;
    const short8 aq0 = *(const short8*)qp;
    const short8 aq1 = *(const short8*)(qp + 32);

    // prologue: stage K/V tile 0 and the initial 128-delta rel window
#pragma unroll
    for (int kk = 0; kk < 2; ++kk) {
        const unsigned short* gp = Kbase + (size_t)(w * 16 + c) * HDD + kk * 32 + quad * 8;
        *(short8*)&Ks[(w * 2 + kk) * 512 + lane * 8] = *(const short8*)gp;
    }
#pragma unroll
    for (int js = 0; js < 2; ++js) {
        const unsigned short* gp = Vbase + (size_t)(w * 16 + c) * TT + js * 32 + quad * 8;
        *(short8*)&Vs[(w * 2 + js) * 512 + lane * 8] = *(const short8*)gp;
    }
    {
        const int mb0 = i0 - 63;
#pragma unroll
        for (int sb = 0; sb < 2; ++sb) {
#pragma unroll
            for (int kk = 0; kk < 2; ++kk) {
                const int n16 = w * 2 + sb;
                int mrow = mb0 + n16 * 16 + c;
                mrow = mrow < 0 ? 0 : (mrow > 511 ? 511 : mrow);
                *(short8*)&Rels[(n16 * 2 + kk) * 512 + lane * 8] =
                    *(const short8*)(Rbase + (size_t)mrow * CC + kk * 32 + quad * 8);
            }
        }
    }

    f32x4 oacc[4];
    float m_i[4], l_i[4];
#pragma unroll
    for (int r = 0; r < 4; ++r) { m_i[r] = -1e30f; l_i[r] = 0.f; }
#pragma unroll
    for (int nd = 0; nd < 4; ++nd) oacc[nd] = (f32x4){0.f, 0.f, 0.f, 0.f};

    __syncthreads();

    for (int jt = 0; jt <= qt; ++jt) {
        const int j0 = jt * 64;

        short8 pK0, pK1, pV0, pV1, pR0, pR1;
        if (jt < qt) {
            const int j1 = j0 + 64;
            const unsigned short* kp = Kbase + (size_t)(j1 + w * 16 + c) * HDD + quad * 8;
            pK0 = *(const short8*)kp;
            pK1 = *(const short8*)(kp + 32);
            const unsigned short* vp = Vbase + (size_t)(w * 16 + c) * TT + j1 + quad * 8;
            pV0 = *(const short8*)vp;
            pV1 = *(const short8*)(vp + 32);
            int mr = i0 - j1 - 63 + w * 16 + c;
            mr = mr < 0 ? 0 : (mr > 511 ? 511 : mr);
            const unsigned short* rp = Rbase + (size_t)mr * CC + quad * 8;
            pR0 = *(const short8*)rp;
            pR1 = *(const short8*)(rp + 32);
        }

        // S = Q @ K^T (log2 domain)
        f32x4 sAcc[4];
#pragma unroll
        for (int ns = 0; ns < 4; ++ns) {
            const short8 bk0 = *(const short8*)&Ks[(ns * 2 + 0) * 512 + lane * 8];
            const short8 bk1 = *(const short8*)&Ks[(ns * 2 + 1) * 512 + lane * 8];
            f32x4 a2 = (f32x4){0.f, 0.f, 0.f, 0.f};
            a2 = __builtin_amdgcn_mfma_f32_16x16x32_bf16(aq0, bk0, a2, 0, 0, 0);
            a2 = __builtin_amdgcn_mfma_f32_16x16x32_bf16(aq1, bk1, a2, 0, 0, 0);
            sAcc[ns] = a2;
        }
        // RD: only new delta subtiles
        const int mbase = i0 - j0 - 63;
        if (jt == 0) {
#pragma unroll
            for (int nr = 0; nr < 8; ++nr) RD_BODY(nr)
        } else {
#pragma unroll
            for (int nr = 0; nr < 4; ++nr) RD_BODY(nr)
        }

        // gather rel bias (circular col = delta & 127)
        const int dbase = i0 - j0;
        float sc[4][4];
#pragma unroll
        for (int ns = 0; ns < 4; ++ns) {
#pragma unroll
            for (int r = 0; r < 4; ++r) {
                const int r16 = quad * 4 + r;
                const int jc = ns * 16 + c;
                const int dp = (dbase + w * 16 + r16 - jc) & 127;
                const float rdv = bf2f(RDs[w][r16 * 132 + dp]);
                sc[ns][r] = sAcc[ns][r] + rdv;
            }
        }
        if (jt == qt) {   // causal mask exists only on the diagonal tile
#pragma unroll
            for (int ns = 0; ns < 4; ++ns)
#pragma unroll
                for (int r = 0; r < 4; ++r)
                    if (ns * 16 + c > w * 16 + quad * 4 + r) sc[ns][r] = -1e30f;
        }

        float alpha[4];
#pragma unroll
        for (int r = 0; r < 4; ++r) {
            float m = fmaxf(fmaxf(sc[0][r], sc[1][r]), fmaxf(sc[2][r], sc[3][r]));
#pragma unroll
            for (int off = 1; off < 16; off <<= 1) m = fmaxf(m, __shfl_xor(m, off));
            const float mn = fmaxf(m_i[r], m);
            alpha[r] = exp2f(m_i[r] - mn);
            m_i[r] = mn;
        }
        float rs[4] = {0.f, 0.f, 0.f, 0.f};
#pragma unroll
        for (int ns = 0; ns < 4; ++ns) {
#pragma unroll
            for (int r = 0; r < 4; ++r) {
                const float p = exp2f(sc[ns][r] - m_i[r]);
                rs[r] += p;
                Ps[w][(quad * 4 + r) * 72 + ns * 16 + c] = f2bf(p);
            }
        }
#pragma unroll
        for (int r = 0; r < 4; ++r) {
#pragma unroll
            for (int off = 1; off < 16; off <<= 1) rs[r] += __shfl_xor(rs[r], off);
            l_i[r] = l_i[r] * alpha[r] + rs[r];
        }
#pragma unroll
        for (int nd = 0; nd < 4; ++nd)
#pragma unroll
            for (int r = 0; r < 4; ++r) oacc[nd][r] *= alpha[r];

        const short8 ap0 = *(const short8*)&Ps[w][c * 72 + 0 * 32 + quad * 8];
        const short8 ap1 = *(const short8*)&Ps[w][c * 72 + 1 * 32 + quad * 8];
#pragma unroll
        for (int nd = 0; nd < 4; ++nd) {
            const short8 bv0 = *(const short8*)&Vs[(nd * 2 + 0) * 512 + lane * 8];
            const short8 bv1 = *(const short8*)&Vs[(nd * 2 + 1) * 512 + lane * 8];
            oacc[nd] = __builtin_amdgcn_mfma_f32_16x16x32_bf16(ap0, bv0, oacc[nd], 0, 0, 0);
            oacc[nd] = __builtin_amdgcn_mfma_f32_16x16x32_bf16(ap1, bv1, oacc[nd], 0, 0, 0);
        }

        if (jt < qt) {
            __syncthreads();
#pragma unroll
            for (int kk = 0; kk < 2; ++kk)
                *(short8*)&Ks[(w * 2 + kk) * 512 + lane * 8] = (kk ? pK1 : pK0);
#pragma unroll
            for (int js = 0; js < 2; ++js)
                *(short8*)&Vs[(w * 2 + js) * 512 + lane * 8] = (js ? pV1 : pV0);
#pragma unroll
            for (int kk = 0; kk < 2; ++kk)
                *(short8*)&Rels[(w * 2 + kk) * 512 + lane * 8] = (kk ? pR1 : pR0);
            __syncthreads();
        }
    }

    // epilogue: Yb[b][t][h*64 + d] bf16
#pragma unroll
    for (int r = 0; r < 4; ++r) {
        const float inv = 1.f / l_i[r];
        const int trow = i0 + w * 16 + quad * 4 + r;
        unsigned short* yb = Yb + ((size_t)b * TT + trow) * CC + h * HDD;
#pragma unroll
        for (int nd = 0; nd < 4; ++nd)
            yb[nd * 16 + c] = f2bf(oacc[nd][r] * inv);
    }
}

// ---------------------------------------------------------------------------
// Kernel 3: out = Yb @ Wpb^T + b_proj.
//   R9: B-direct-to-register structure (same as qkvln). 32x256 tile, grid
//   256 = 2 col-halves x 128 row-slabs = 1 block/CU. A (Yb bf16) via 4KB LDS,
//   B (Wpb) global->reg double-buffered. MFMA-bound (~310cy vs B-L2 ~237cy).
// ---------------------------------------------------------------------------
#define PLOADB(bN, koff)                                                      \
    _Pragma("unroll")                                                         \
    for (int kk = 0; kk < 2; ++kk)                                            \
        _Pragma("unroll")                                                     \
        for (int j = 0; j < 4; ++j)                                           \
            bN[kk * 4 + j] =                                                  \
                *(const short8*)(Bb + (size_t)j * 8192 + kk * 32 + (koff));

#define PSTAGE_A()                                                            \
    __syncthreads();                                                          \
    *(short8*)&Alds[dstA] = apre;                                             \
    __syncthreads();

#define PCOMPUTE(bN)                                                          \
    _Pragma("unroll")                                                         \
    for (int kk = 0; kk < 2; ++kk) {                                          \
        short8 af[2];                                                         \
        _Pragma("unroll")                                                     \
        for (int i = 0; i < 2; ++i)                                           \
            af[i] = *(const short8*)&Alds[((i << 1) | kk) * 512 + lane * 8];  \
        _Pragma("unroll")                                                     \
        for (int j = 0; j < 4; ++j)                                           \
            _Pragma("unroll")                                                 \
            for (int i = 0; i < 2; ++i)                                       \
                acc[i][j] = __builtin_amdgcn_mfma_f32_16x16x32_bf16(          \
                    af[i], bN[kk * 4 + j], acc[i][j], 0, 0, 0);               \
    }

__global__ __launch_bounds__(256, 1) void gemm_proj_k(
    const unsigned short* __restrict__ Yb, const unsigned short* __restrict__ Wpb,
    const float* __restrict__ bias, float* __restrict__ out)
{
    __shared__ __align__(16) unsigned short Alds[4 * 512];

    const int tid = threadIdx.x;
    const int w = tid >> 6, lane = tid & 63;
    const int c = lane & 15, quad = lane >> 4;
    const int colh = blockIdx.x >> 7, slab = blockIdx.x & 127;
    const int row0 = slab * 32;
    const int ncol0 = colh * 256 + w * 64;

    const int fr = tid >> 6, li = tid & 63;
    const unsigned short* srcA =
        Yb + (size_t)(row0 + (fr >> 1) * 16 + (li & 15)) * 512
           + (fr & 1) * 32 + (li >> 4) * 8;
    const int dstA = fr * 512 + li * 8;
    const unsigned short* Bb = Wpb + (size_t)(ncol0 + c) * 512 + quad * 8;

    f32x4 acc[2][4];
#pragma unroll
    for (int i = 0; i < 2; ++i)
#pragma unroll
        for (int j = 0; j < 4; ++j) acc[i][j] = (f32x4){0.f, 0.f, 0.f, 0.f};

    short8 apre = *(const short8*)srcA;
    short8 b0[8], b1[8];
    PLOADB(b0, 0);

#pragma unroll
    for (int kp = 0; kp < 4; ++kp) {
        const int ka = kp * 128;
        PSTAGE_A();
        if (true) { apre = *(const short8*)(srcA + ka + 64); }
        PLOADB(b1, ka + 64);
        PCOMPUTE(b0);
        PSTAGE_A();
        if (kp < 3) {
            apre = *(const short8*)(srcA + ka + 128);
            PLOADB(b0, ka + 128);
        }
        PCOMPUTE(b1);
    }

#pragma unroll
    for (int j = 0; j < 4; ++j) {
        const int gc = ncol0 + j * 16 + c;
        const float bj = bias[gc];
#pragma unroll
        for (int i = 0; i < 2; ++i)
#pragma unroll
            for (int r = 0; r < 4; ++r)
                out[(size_t)(row0 + i * 16 + quad * 4 + r) * 512 + gc] =
                    acc[i][j][r] + bj;
    }
}

// ---------------------------------------------------------------------------
extern "C" void kernel_launch(void* const* d_in, const int* in_sizes, int n_in,
                              void* d_out, int out_size, void* d_ws, size_t ws_size,
                              hipStream_t stream)
{
    const float* x      = (const float*)d_in[0];
    const float* w_attn = (const float*)d_in[1];
    const float* b_attn = (const float*)d_in[2];
    const float* w_proj = (const float*)d_in[3];
    const float* b_proj = (const float*)d_in[4];
    const float* q_g    = (const float*)d_in[5];
    const float* q_b    = (const float*)d_in[6];
    const float* k_g    = (const float*)d_in[7];
    const float* k_b    = (const float*)d_in[8];
    const float* rel    = (const float*)d_in[9];
    float* out = (float*)d_out;

    // workspace (~19.4 MB bf16): Qh 4MB | Kh 4 | VT 4 | Yb 4 | Relb 0.5 |
    //   Wqb 1.5 | Wpb 0.5
    unsigned short* Qh   = (unsigned short*)d_ws;
    unsigned short* Kh   = Qh + (size_t)4096 * 512;
    unsigned short* VT   = Kh + (size_t)4096 * 512;
    unsigned short* Yb   = VT + (size_t)4096 * 512;
    unsigned short* Relb = Yb + (size_t)4096 * 512;
    unsigned short* Wqb  = Relb + (size_t)512 * 512;
    unsigned short* Wpb  = Wqb + (size_t)1536 * 512;

    cvt_w_k<<<1280, 256, 0, stream>>>(w_attn, w_proj, rel, Wqb, Wpb, Relb);
    qkvln_k<<<192, 256, 0, stream>>>(x, Wqb, b_attn, q_g, q_b, k_g, k_b, Qh, Kh, VT);
    attn_k<<<512, 256, 0, stream>>>(Qh, Kh, VT, Relb, Yb);
    gemm_proj_k<<<256, 256, 0, stream>>>(Yb, Wpb, b_proj, out);
}